// Round 1
// baseline (323.804 us; speedup 1.0000x reference)
//
#include <hip/hip_runtime.h>
#include <stdint.h>

// Problem constants: B=1, N=4096, C=256, H=8, D=64, H*D=512
#define NN 4096
#define CC 256
#define HD 512
#define DD 64

typedef __attribute__((ext_vector_type(8))) short short8;
typedef __attribute__((ext_vector_type(4))) float floatx4;

__device__ __forceinline__ unsigned short f2bf(float x) {
    union { float f; unsigned int u; } v; v.f = x;
    unsigned int u = v.u + 0x7fffu + ((v.u >> 16) & 1u);
    return (unsigned short)(u >> 16);
}
__device__ __forceinline__ float bf2f(unsigned short s) {
    union { unsigned int u; float f; } v; v.u = ((unsigned int)s) << 16;
    return v.f;
}

// ---------------------------------------------------------------------------
// Kernel 1: projections. C_out[i][j] = act( sum_c X[i][c] * W[j][c] )
// mode 0: Q = (qx@wq^T)*0.125 ; 1: K = kx@wk^T ; 2: V = vx@wv^T ;
// mode 3: G = sigmoid(qx@wg^T + bg). All outputs bf16 [4096][512].
// Tile 64x64, BK=64, 256 threads (4 waves), wave owns a 16-row strip.
// ---------------------------------------------------------------------------
__global__ __launch_bounds__(256) void proj_kernel(
    const float* __restrict__ qx, const float* __restrict__ kx,
    const float* __restrict__ vx,
    const float* __restrict__ wq, const float* __restrict__ wk,
    const float* __restrict__ wv, const float* __restrict__ wg,
    const float* __restrict__ bg,
    unsigned short* __restrict__ Qb, unsigned short* __restrict__ Kb,
    unsigned short* __restrict__ Vb, unsigned short* __restrict__ Gb)
{
    const int mode = blockIdx.z;
    const float* X = (mode == 1) ? kx : (mode == 2) ? vx : qx;
    const float* W = (mode == 0) ? wq : (mode == 1) ? wk : (mode == 2) ? wv : wg;
    unsigned short* Out = (mode == 0) ? Qb : (mode == 1) ? Kb : (mode == 2) ? Vb : Gb;

    const int m0 = blockIdx.x * 64;
    const int n0 = blockIdx.y * 64;
    const int tid = threadIdx.x;
    const int wid = tid >> 6;
    const int lane = tid & 63;
    const int quad = lane >> 4;
    const int ln = lane & 15;

    // +8 pad keeps 16B alignment and breaks the 32-bank stride
    __shared__ __align__(16) unsigned short Xs[64 * 72];
    __shared__ __align__(16) unsigned short Ws[64 * 72];

    floatx4 acc[4] = {};

    for (int k0 = 0; k0 < CC; k0 += 64) {
        // stage X tile (64x64 fp32 -> bf16)
        #pragma unroll
        for (int i = 0; i < 4; i++) {
            int idx = i * 256 + tid;
            int r = idx >> 4, c4 = idx & 15;
            float4 x4 = *(const float4*)&X[(size_t)(m0 + r) * CC + k0 + c4 * 4];
            ushort4 p;
            p.x = f2bf(x4.x); p.y = f2bf(x4.y); p.z = f2bf(x4.z); p.w = f2bf(x4.w);
            *(ushort4*)&Xs[r * 72 + c4 * 4] = p;
        }
        // stage W tile (rows n0..n0+63 of [512][256])
        #pragma unroll
        for (int i = 0; i < 4; i++) {
            int idx = i * 256 + tid;
            int r = idx >> 4, c4 = idx & 15;
            float4 w4 = *(const float4*)&W[(size_t)(n0 + r) * CC + k0 + c4 * 4];
            ushort4 p;
            p.x = f2bf(w4.x); p.y = f2bf(w4.y); p.z = f2bf(w4.z); p.w = f2bf(w4.w);
            *(ushort4*)&Ws[r * 72 + c4 * 4] = p;
        }
        __syncthreads();

        #pragma unroll
        for (int ks = 0; ks < 64; ks += 32) {
            short8 a = *(const short8*)&Xs[(wid * 16 + ln) * 72 + ks + quad * 8];
            #pragma unroll
            for (int n = 0; n < 4; n++) {
                short8 b = *(const short8*)&Ws[(n * 16 + ln) * 72 + ks + quad * 8];
                acc[n] = __builtin_amdgcn_mfma_f32_16x16x32_bf16(a, b, acc[n], 0, 0, 0);
            }
        }
        __syncthreads();
    }

    // epilogue: C/D layout col = ln, row = quad*4 + r (within 16-row tile)
    #pragma unroll
    for (int n = 0; n < 4; n++) {
        int col = n0 + n * 16 + ln;
        float bgv = (mode == 3) ? bg[col] : 0.0f;
        #pragma unroll
        for (int r = 0; r < 4; r++) {
            int row = m0 + wid * 16 + quad * 4 + r;
            float v = acc[n][r];
            if (mode == 0)      v *= 0.125f;           // 1/sqrt(64)
            else if (mode == 3) v = 1.0f / (1.0f + __expf(-(v + bgv)));
            Out[(size_t)row * HD + col] = f2bf(v);
        }
    }
}

// ---------------------------------------------------------------------------
// Kernel 2: flash attention + gating. Block = (64 q-rows, 1 head), Tk = 128.
// S = Q K^T (MFMA) + bias (fp32), online softmax, P->LDS->A-layout, O += P V.
// Epilogue: O/l * g -> OG bf16 [4096][512].
// ---------------------------------------------------------------------------
__global__ __launch_bounds__(256) void attn_kernel(
    const unsigned short* __restrict__ Qb, const unsigned short* __restrict__ Kb,
    const unsigned short* __restrict__ Vb, const unsigned short* __restrict__ Gb,
    const float* __restrict__ bias, unsigned short* __restrict__ OGb)
{
    const int h = blockIdx.y;
    const int q0 = blockIdx.x * 64;
    const int tid = threadIdx.x;
    const int wid = tid >> 6;
    const int lane = tid & 63;
    const int quad = lane >> 4;
    const int ln = lane & 15;

    __shared__ __align__(16) unsigned short Qs[64 * 72];    //  9216 B
    __shared__ __align__(16) unsigned short Ks[128 * 72];   // 18432 B
    __shared__ __align__(16) unsigned short Vs[64 * 136];   // 17408 B (transposed: [d][key])
    __shared__ __align__(16) unsigned short Ps[64 * 136];   // 17408 B

    // stage Q once (64 rows x 64 bf16 for this head)
    #pragma unroll
    for (int i = 0; i < 2; i++) {
        int idx = i * 256 + tid;
        int r = idx >> 3, c8 = idx & 7;
        short8 qv = *(const short8*)&Qb[(size_t)(q0 + r) * HD + h * DD + c8 * 8];
        *(short8*)&Qs[r * 72 + c8 * 8] = qv;
    }

    floatx4 O[4] = {};            // D-subtiles, C-layout
    float m_run[4], l_run[4];     // rows: wid*16 + quad*4 + r
    #pragma unroll
    for (int r = 0; r < 4; r++) { m_run[r] = -1e30f; l_run[r] = 0.0f; }

    for (int k0 = 0; k0 < NN; k0 += 128) {
        // stage K tile (128 keys x 64 d)
        #pragma unroll
        for (int i = 0; i < 4; i++) {
            int idx = i * 256 + tid;
            int r = idx >> 3, c8 = idx & 7;
            short8 kv = *(const short8*)&Kb[(size_t)(k0 + r) * HD + h * DD + c8 * 8];
            *(short8*)&Ks[r * 72 + c8 * 8] = kv;
        }
        // stage V transposed: Vs[d][key]
        #pragma unroll
        for (int i = 0; i < 4; i++) {
            int idx = i * 256 + tid;
            int key = idx >> 3, d8 = idx & 7;
            short8 vv = *(const short8*)&Vb[(size_t)(k0 + key) * HD + h * DD + d8 * 8];
            #pragma unroll
            for (int j = 0; j < 8; j++)
                Vs[(d8 * 8 + j) * 136 + key] = (unsigned short)vv[j];
        }
        __syncthreads();

        // S[64][128]: wave owns 16 q-rows, 8 key-subtiles of 16
        floatx4 S[8] = {};
        #pragma unroll
        for (int ks = 0; ks < 64; ks += 32) {
            short8 a = *(const short8*)&Qs[(wid * 16 + ln) * 72 + ks + quad * 8];
            #pragma unroll
            for (int n = 0; n < 8; n++) {
                short8 b = *(const short8*)&Ks[(n * 16 + ln) * 72 + ks + quad * 8];
                S[n] = __builtin_amdgcn_mfma_f32_16x16x32_bf16(a, b, S[n], 0, 0, 0);
            }
        }

        // bias + online softmax (per row r; row data lives in this quad's 16 lanes)
        #pragma unroll
        for (int r = 0; r < 4; r++) {
            int grow = q0 + wid * 16 + quad * 4 + r;
            const float* brow = &bias[(size_t)grow * NN + k0];
            float t[8];
            float mx = -1e30f;
            #pragma unroll
            for (int n = 0; n < 8; n++) {
                t[n] = S[n][r] + brow[n * 16 + ln];
                mx = fmaxf(mx, t[n]);
            }
            #pragma unroll
            for (int off = 1; off < 16; off <<= 1)
                mx = fmaxf(mx, __shfl_xor(mx, off));
            float mnew  = fmaxf(m_run[r], mx);
            float alpha = __expf(m_run[r] - mnew);
            float rs = 0.0f;
            #pragma unroll
            for (int n = 0; n < 8; n++) {
                float p = __expf(t[n] - mnew);
                rs += p;
                Ps[(wid * 16 + quad * 4 + r) * 136 + n * 16 + ln] = f2bf(p);
            }
            #pragma unroll
            for (int off = 1; off < 16; off <<= 1)
                rs += __shfl_xor(rs, off);
            l_run[r] = l_run[r] * alpha + rs;
            m_run[r] = mnew;
            #pragma unroll
            for (int nd = 0; nd < 4; nd++) O[nd][r] *= alpha;
        }
        __syncthreads();   // Ps visible (same-wave anyway; cheap safety)

        // O += P V : A = Ps rows (own q-rows), B = Vs rows (d), k = key
        #pragma unroll
        for (int ks = 0; ks < 128; ks += 32) {
            short8 a = *(const short8*)&Ps[(wid * 16 + ln) * 136 + ks + quad * 8];
            #pragma unroll
            for (int nd = 0; nd < 4; nd++) {
                short8 b = *(const short8*)&Vs[(nd * 16 + ln) * 136 + ks + quad * 8];
                O[nd] = __builtin_amdgcn_mfma_f32_16x16x32_bf16(a, b, O[nd], 0, 0, 0);
            }
        }
        __syncthreads();   // done with Ks/Vs before next stage
    }

    // epilogue: normalize, gate, store bf16
    #pragma unroll
    for (int r = 0; r < 4; r++) {
        int grow = q0 + wid * 16 + quad * 4 + r;
        float inv = 1.0f / l_run[r];
        #pragma unroll
        for (int nd = 0; nd < 4; nd++) {
            int col = h * DD + nd * 16 + ln;
            float g = bf2f(Gb[(size_t)grow * HD + col]);
            float v = O[nd][r] * inv * g;
            OGb[(size_t)grow * HD + col] = f2bf(v);
        }
    }
}

// ---------------------------------------------------------------------------
// Kernel 3: out = OG[4096][512](bf16) @ wo^T([256][512] fp32) + bo -> fp32
// ---------------------------------------------------------------------------
__global__ __launch_bounds__(256) void outproj_kernel(
    const unsigned short* __restrict__ OGb, const float* __restrict__ wo,
    const float* __restrict__ bo, float* __restrict__ out)
{
    const int m0 = blockIdx.x * 64;
    const int n0 = blockIdx.y * 64;
    const int tid = threadIdx.x;
    const int wid = tid >> 6;
    const int lane = tid & 63;
    const int quad = lane >> 4;
    const int ln = lane & 15;

    __shared__ __align__(16) unsigned short Xs[64 * 72];
    __shared__ __align__(16) unsigned short Ws[64 * 72];

    floatx4 acc[4] = {};

    for (int k0 = 0; k0 < HD; k0 += 64) {
        // stage OG tile (already bf16)
        #pragma unroll
        for (int i = 0; i < 2; i++) {
            int idx = i * 256 + tid;
            int r = idx >> 3, c8 = idx & 7;
            *(short8*)&Xs[r * 72 + c8 * 8] =
                *(const short8*)&OGb[(size_t)(m0 + r) * HD + k0 + c8 * 8];
        }
        // stage wo tile (fp32 -> bf16), rows n0..n0+63 of [256][512]
        #pragma unroll
        for (int i = 0; i < 4; i++) {
            int idx = i * 256 + tid;
            int r = idx >> 4, c4 = idx & 15;
            float4 w4 = *(const float4*)&wo[(size_t)(n0 + r) * HD + k0 + c4 * 4];
            ushort4 p;
            p.x = f2bf(w4.x); p.y = f2bf(w4.y); p.z = f2bf(w4.z); p.w = f2bf(w4.w);
            *(ushort4*)&Ws[r * 72 + c4 * 4] = p;
        }
        __syncthreads();

        #pragma unroll
        for (int ks = 0; ks < 64; ks += 32) {
            short8 a = *(const short8*)&Xs[(wid * 16 + ln) * 72 + ks + quad * 8];
            #pragma unroll
            for (int n = 0; n < 4; n++) {
                short8 b = *(const short8*)&Ws[(n * 16 + ln) * 72 + ks + quad * 8];
                acc[n] = __builtin_amdgcn_mfma_f32_16x16x32_bf16(a, b, acc[n], 0, 0, 0);
            }
        }
        __syncthreads();
    }

    #pragma unroll
    for (int n = 0; n < 4; n++) {
        int col = n0 + n * 16 + ln;
        float bov = bo[col];
        #pragma unroll
        for (int r = 0; r < 4; r++) {
            int row = m0 + wid * 16 + quad * 4 + r;
            out[(size_t)row * CC + col] = acc[n][r] + bov;
        }
    }
}

// ---------------------------------------------------------------------------
extern "C" void kernel_launch(void* const* d_in, const int* in_sizes, int n_in,
                              void* d_out, int out_size, void* d_ws, size_t ws_size,
                              hipStream_t stream) {
    const float* qx   = (const float*)d_in[0];
    const float* kx   = (const float*)d_in[1];
    const float* vx   = (const float*)d_in[2];
    const float* bias = (const float*)d_in[3];
    const float* wq   = (const float*)d_in[4];
    const float* wk   = (const float*)d_in[5];
    const float* wv   = (const float*)d_in[6];
    const float* wg   = (const float*)d_in[7];
    const float* bg   = (const float*)d_in[8];
    const float* wo   = (const float*)d_in[9];
    const float* bo   = (const float*)d_in[10];
    float* out = (float*)d_out;

    char* ws = (char*)d_ws;
    unsigned short* Qb  = (unsigned short*)(ws);                  // 4 MB each
    unsigned short* Kb  = (unsigned short*)(ws + ((size_t)4  << 20));
    unsigned short* Vb  = (unsigned short*)(ws + ((size_t)8  << 20));
    unsigned short* Gb  = (unsigned short*)(ws + ((size_t)12 << 20));
    unsigned short* OGb = (unsigned short*)(ws + ((size_t)16 << 20));

    proj_kernel<<<dim3(64, 8, 4), 256, 0, stream>>>(
        qx, kx, vx, wq, wk, wv, wg, bg, Qb, Kb, Vb, Gb);
    attn_kernel<<<dim3(64, 8), 256, 0, stream>>>(
        Qb, Kb, Vb, Gb, bias, OGb);
    outproj_kernel<<<dim3(64, 4), 256, 0, stream>>>(
        OGb, wo, bo, out);
}